// Round 4
// baseline (1270.319 us; speedup 1.0000x reference)
//
#include <hip/hip_runtime.h>

#define HIDDEN 1024
#define FFN    4096
#define NEXP   8
#define NTOK   16384
#define CAP    16384
#define NPAIRS (2*NTOK)

#define BM 256
#define BN 256
#define BK 64

typedef _Float16 f16;
typedef _Float16 f16x8 __attribute__((ext_vector_type(8)));
typedef float    f32x4 __attribute__((ext_vector_type(4)));

typedef __attribute__((address_space(1))) const unsigned int gu32;
typedef __attribute__((address_space(3))) unsigned int lu32;

__device__ __forceinline__ void gll16(const void* g, void* l) {
  // async global->LDS, 16B/lane; LDS dest = wave-uniform base + lane*16
  __builtin_amdgcn_global_load_lds((gu32*)g, (lu32*)l, 16, 0, 0);
}

// ---------------- utility kernels ----------------

__global__ void k_sentinel(float* out) { if (threadIdx.x == 0) out[0] = -1e30f; }

__global__ void k_zero(float4* out, int n4) {
  int i = blockIdx.x * blockDim.x + threadIdx.x;
  int tot = gridDim.x * blockDim.x;
  for (int j = i; j < n4; j += tot) out[j] = float4{0.f, 0.f, 0.f, 0.f};
}

__global__ void k_cvt(const float* __restrict__ in, f16* __restrict__ out, int n8) {
  int i = blockIdx.x * blockDim.x + threadIdx.x;
  int tot = gridDim.x * blockDim.x;
  for (int j = i; j < n8; j += tot) {
    float4 a = ((const float4*)in)[2 * j];
    float4 b = ((const float4*)in)[2 * j + 1];
    f16x8 v = {(f16)a.x, (f16)a.y, (f16)a.z, (f16)a.w,
               (f16)b.x, (f16)b.y, (f16)b.z, (f16)b.w};
    ((f16x8*)out)[j] = v;
  }
}

__global__ void k_trans(const float* __restrict__ in, f16* __restrict__ out, int R, int C) {
  __shared__ float t[32][33];
  int z = blockIdx.z;
  const float* I = in + (size_t)z * R * C;
  f16* O = out + (size_t)z * R * C;
  int c0 = blockIdx.x * 32, r0 = blockIdx.y * 32;
  int tx = threadIdx.x & 31, ty = threadIdx.x >> 5;  // 32 x 8
  #pragma unroll
  for (int i = 0; i < 32; i += 8)
    t[ty + i][tx] = I[(size_t)(r0 + ty + i) * C + c0 + tx];
  __syncthreads();
  #pragma unroll
  for (int i = 0; i < 32; i += 8)
    O[(size_t)(c0 + ty + i) * R + r0 + tx] = (f16)t[tx][ty + i];
}

__global__ void k_gate(const float* __restrict__ x, const float* __restrict__ Wg,
                       const float* __restrict__ bg, int2* __restrict__ toke,
                       float2* __restrict__ tokw) {
  int wid = threadIdx.x >> 6, lane = threadIdx.x & 63;
  int tok = blockIdx.x * 4 + wid;
  const float* xr = x + (size_t)tok * HIDDEN;
  float s[8] = {0.f, 0.f, 0.f, 0.f, 0.f, 0.f, 0.f, 0.f};
  for (int j = lane; j < HIDDEN; j += 64) {
    float xv = xr[j];
    const float4* wr = (const float4*)(Wg + j * 8);
    float4 wa = wr[0], wb = wr[1];
    s[0] += xv * wa.x; s[1] += xv * wa.y; s[2] += xv * wa.z; s[3] += xv * wa.w;
    s[4] += xv * wb.x; s[5] += xv * wb.y; s[6] += xv * wb.z; s[7] += xv * wb.w;
  }
  #pragma unroll
  for (int off = 32; off > 0; off >>= 1) {
    #pragma unroll
    for (int e = 0; e < 8; ++e) s[e] += __shfl_down(s[e], off);
  }
  if (lane == 0) {
    float best = -1e30f, second = -1e30f;
    int bi = 0, si = 0;
    #pragma unroll
    for (int e = 0; e < 8; ++e) {
      float v = s[e] + bg[e];
      if (v > best)        { second = best; si = bi; best = v; bi = e; }
      else if (v > second) { second = v; si = e; }
    }
    float p = expf(second - best);
    float inv = 1.0f / (1.0f + p);
    toke[tok] = make_int2(bi, si);
    tokw[tok] = make_float2(inv, p * inv);
  }
}

__global__ void k_build(const int2* __restrict__ toke, const float2* __restrict__ tokw,
                        int* __restrict__ pair_tok, float* __restrict__ pair_w,
                        int* __restrict__ counts) {
  int e = blockIdx.x;
  __shared__ int cursor;
  if (threadIdx.x == 0) cursor = 0;
  __syncthreads();
  for (int i = threadIdx.x; i < NTOK; i += blockDim.x) {
    int2 ee = toke[i];
    float2 ww = tokw[i];
    if (ee.x == e) { int p = atomicAdd(&cursor, 1); pair_tok[e * CAP + p] = i; pair_w[e * CAP + p] = ww.x; }
    if (ee.y == e) { int p = atomicAdd(&cursor, 1); pair_tok[e * CAP + p] = i; pair_w[e * CAP + p] = ww.y; }
  }
  __syncthreads();
  if (threadIdx.x == 0) counts[e] = cursor;
}

// ---------------- 256x256 BK=64 8-wave double-buffered GEMM core ----------------
// T2: LDS rows are 128B (one bank period); slot^=(row&7) applied at BOTH the
// gll16 per-lane SOURCE address and the ds_read address (both-sides involution).
// T4: steady-state wait = vmcnt(8) (tile t landed, tile t+1's 8 loads in flight).
// Raw s_barrier + sched_barrier(0) fences; NO __syncthreads (would drain vmcnt).
__device__ __forceinline__ void gemm_core(
    const f16* const (&aS)[4], const f16* const (&bS)[4],
    f16* lsA0, f16* lsA1, f16* lsB0, f16* lsB1,
    int nt, int sbase, int ra0, int rb0, int sx0, int sx1,
    f32x4 (&acc)[8][4]) {
  // prologue: stage tile0 -> buf0, tile1 -> buf1 (16 loads/wave in flight)
  #pragma unroll
  for (int c = 0; c < 4; ++c) {
    gll16(aS[c], lsA0 + sbase + c * 512);
    gll16(bS[c], lsB0 + sbase + c * 512);
  }
  #pragma unroll
  for (int c = 0; c < 4; ++c) {
    gll16(aS[c] + 64, lsA1 + sbase + c * 512);
    gll16(bS[c] + 64, lsB1 + sbase + c * 512);
  }
  for (int t = 0; t < nt; ++t) {
    const f16* LA = (t & 1) ? lsA1 : lsA0;
    const f16* LB = (t & 1) ? lsB1 : lsB0;
    if (t + 1 < nt) asm volatile("s_waitcnt vmcnt(8)" ::: "memory");
    else            asm volatile("s_waitcnt vmcnt(0)" ::: "memory");
    __builtin_amdgcn_sched_barrier(0);
    __builtin_amdgcn_s_barrier();          // all waves: tile t visible, tile t-2 reads done
    __builtin_amdgcn_sched_barrier(0);

    f16x8 af[4][2], bf[4][2];
    #pragma unroll
    for (int nf = 0; nf < 4; ++nf) {       // hold ALL of B for the tile (32 VGPR)
      bf[nf][0] = *(const f16x8*)(LB + rb0 + nf * 1024 + sx0);
      bf[nf][1] = *(const f16x8*)(LB + rb0 + nf * 1024 + sx1);
    }
    #pragma unroll
    for (int m = 0; m < 4; ++m) {          // A m-half 0
      af[m][0] = *(const f16x8*)(LA + ra0 + m * 1024 + sx0);
      af[m][1] = *(const f16x8*)(LA + ra0 + m * 1024 + sx1);
    }
    __builtin_amdgcn_s_setprio(1);
    #pragma unroll
    for (int m = 0; m < 4; ++m)
      #pragma unroll
      for (int nf = 0; nf < 4; ++nf)
        acc[m][nf] = __builtin_amdgcn_mfma_f32_16x16x32_f16(af[m][0], bf[nf][0], acc[m][nf], 0, 0, 0);
    __builtin_amdgcn_s_setprio(0);
    __builtin_amdgcn_s_setprio(1);
    #pragma unroll
    for (int m = 0; m < 4; ++m)
      #pragma unroll
      for (int nf = 0; nf < 4; ++nf)
        acc[m][nf] = __builtin_amdgcn_mfma_f32_16x16x32_f16(af[m][1], bf[nf][1], acc[m][nf], 0, 0, 0);
    __builtin_amdgcn_s_setprio(0);

    #pragma unroll
    for (int m = 0; m < 4; ++m) {          // A m-half 1 (reuse af regs)
      af[m][0] = *(const f16x8*)(LA + ra0 + (m + 4) * 1024 + sx0);
      af[m][1] = *(const f16x8*)(LA + ra0 + (m + 4) * 1024 + sx1);
    }
    asm volatile("s_waitcnt lgkmcnt(0)" ::: "memory");  // all this wave's reads of buf[cur] landed
    __builtin_amdgcn_sched_barrier(0);
    __builtin_amdgcn_s_barrier();          // ALL waves done reading buf[cur] -> safe to overwrite
    __builtin_amdgcn_sched_barrier(0);
    if (t + 2 < nt) {                      // stage tile t+2 into freed buffer; overlaps P2/P3 MFMAs
      f16* SA = (t & 1) ? lsA1 : lsA0;
      f16* SB = (t & 1) ? lsB1 : lsB0;
      #pragma unroll
      for (int c = 0; c < 4; ++c) {
        gll16(aS[c] + (size_t)(t + 2) * 64, SA + sbase + c * 512);
        gll16(bS[c] + (size_t)(t + 2) * 64, SB + sbase + c * 512);
      }
    }
    __builtin_amdgcn_s_setprio(1);
    #pragma unroll
    for (int m = 0; m < 4; ++m)
      #pragma unroll
      for (int nf = 0; nf < 4; ++nf)
        acc[m + 4][nf] = __builtin_amdgcn_mfma_f32_16x16x32_f16(af[m][0], bf[nf][0], acc[m + 4][nf], 0, 0, 0);
    __builtin_amdgcn_s_setprio(0);
    __builtin_amdgcn_s_setprio(1);
    #pragma unroll
    for (int m = 0; m < 4; ++m)
      #pragma unroll
      for (int nf = 0; nf < 4; ++nf)
        acc[m + 4][nf] = __builtin_amdgcn_mfma_f32_16x16x32_f16(af[m][1], bf[nf][1], acc[m + 4][nf], 0, 0, 0);
    __builtin_amdgcn_s_setprio(0);
  }
}

// ---------------- GEMM1: h = relu(Xg @ W1e + b1e) ----------------
__global__ __launch_bounds__(512, 2) void k_ffn1(
    const f16* __restrict__ xh, const f16* __restrict__ w1t,
    const float* __restrict__ b1, f16* __restrict__ hbuf,
    const int* __restrict__ pair_tok, const int* __restrict__ counts) {
  const int e = blockIdx.z;
  const int cnt = counts[e];
  // T1 mapping (B-strip L2 reuse): XCD x = bid&7 gets fixed n in {x, x+8}, m-fast.
  const int bid = blockIdx.x;              // 0..1023
  const int x = bid & 7, j = bid >> 3;     // j 0..127
  const int m0 = (j & 63) * BM;
  const int n0 = (x + 8 * (j >> 6)) * BN;
  if (m0 >= cnt) return;
  int hbase = 0;
  #pragma unroll
  for (int q = 0; q < NEXP; ++q) hbase += (q < e) ? counts[q] : 0;

  __shared__ f16 lsA_[2][BM * BK];
  __shared__ f16 lsB_[2][BN * BK];

  const int tid = threadIdx.x;
  const int lane = tid & 63, wid = tid >> 6;
  const int wr = wid >> 2, wc = wid & 3;
  const int cl = lane & 15, rg = lane >> 4;
  const int sl = lane >> 3, so = lane & 7;
  const int xslot = (so ^ sl) * 8;         // T2 swizzle in the gll16 SOURCE address
  const int sbase = wid * 2048;            // wave's 32-row LDS slice
  const int ra0 = (wr * 128 + cl) * 64;
  const int rb0 = (wc * 64 + cl) * 64;
  const int sx0 = (rg ^ (cl & 7)) * 8;     // T2 swizzle in the ds_read address
  const int sx1 = sx0 ^ 32;

  const int maxr = cnt - 1 - m0;
  const int* toks = pair_tok + e * CAP + m0;
  const f16* bbase = w1t + (size_t)e * FFN * HIDDEN;
  const f16* aS[4]; const f16* bS[4];
  #pragma unroll
  for (int c = 0; c < 4; ++c) {
    int r = wid * 32 + c * 8 + sl;
    aS[c] = xh + (size_t)toks[min(r, maxr)] * HIDDEN + xslot;
    bS[c] = bbase + (size_t)(n0 + r) * HIDDEN + xslot;
  }

  f32x4 acc[8][4];
  #pragma unroll
  for (int m = 0; m < 8; ++m)
    #pragma unroll
    for (int nf = 0; nf < 4; ++nf) acc[m][nf] = (f32x4){0.f, 0.f, 0.f, 0.f};

  gemm_core(aS, bS, lsA_[0], lsA_[1], lsB_[0], lsB_[1],
            HIDDEN / BK, sbase, ra0, rb0, sx0, sx1, acc);

  float bias[4];
  #pragma unroll
  for (int nf = 0; nf < 4; ++nf) bias[nf] = b1[(size_t)e * FFN + n0 + wc * 64 + nf * 16 + cl];
  #pragma unroll
  for (int m = 0; m < 8; ++m) {
    #pragma unroll
    for (int i = 0; i < 4; ++i) {
      int rl = wr * 128 + m * 16 + rg * 4 + i;
      if (m0 + rl < cnt) {
        f16* hp = hbuf + (size_t)(hbase + m0 + rl) * FFN + n0 + wc * 64 + cl;
        #pragma unroll
        for (int nf = 0; nf < 4; ++nf)
          hp[nf * 16] = (f16)fmaxf(acc[m][nf][i] + bias[nf], 0.0f);
      }
    }
  }
}

// ---------------- GEMM2: out += cw * (h @ W2e + b2e) ----------------
__global__ __launch_bounds__(512, 2) void k_ffn2(
    const f16* __restrict__ hbuf, const f16* __restrict__ w2t,
    const float* __restrict__ b2, float* __restrict__ out,
    const int* __restrict__ pair_tok, const float* __restrict__ pair_w,
    const int* __restrict__ counts) {
  const int e = blockIdx.z;
  const int cnt = counts[e];
  // T1 mapping (A-tile L2 reuse): XCD x = bid&7; n-fast within each m; m = x + 8*mq.
  const int bid = blockIdx.x;              // 0..255
  const int x = bid & 7, j = bid >> 3;     // j 0..31
  const int n0 = (j & 3) * BN;
  const int m0 = (x + 8 * (j >> 2)) * BM;
  if (m0 >= cnt) return;
  int hbase = 0;
  #pragma unroll
  for (int q = 0; q < NEXP; ++q) hbase += (q < e) ? counts[q] : 0;

  __shared__ f16 lsA_[2][BM * BK];
  __shared__ f16 lsB_[2][BN * BK];

  const int tid = threadIdx.x;
  const int lane = tid & 63, wid = tid >> 6;
  const int wr = wid >> 2, wc = wid & 3;
  const int cl = lane & 15, rg = lane >> 4;
  const int sl = lane >> 3, so = lane & 7;
  const int xslot = (so ^ sl) * 8;
  const int sbase = wid * 2048;
  const int ra0 = (wr * 128 + cl) * 64;
  const int rb0 = (wc * 64 + cl) * 64;
  const int sx0 = (rg ^ (cl & 7)) * 8;
  const int sx1 = sx0 ^ 32;

  const int maxr = cnt - 1 - m0;
  const f16* bbase = w2t + (size_t)e * HIDDEN * FFN;
  const f16* aS[4]; const f16* bS[4];
  #pragma unroll
  for (int c = 0; c < 4; ++c) {
    int r = wid * 32 + c * 8 + sl;
    aS[c] = hbuf + (size_t)(hbase + m0 + min(r, maxr)) * FFN + xslot;
    bS[c] = bbase + (size_t)(n0 + r) * FFN + xslot;
  }

  f32x4 acc[8][4];
  #pragma unroll
  for (int m = 0; m < 8; ++m)
    #pragma unroll
    for (int nf = 0; nf < 4; ++nf) acc[m][nf] = (f32x4){0.f, 0.f, 0.f, 0.f};

  gemm_core(aS, bS, lsA_[0], lsA_[1], lsB_[0], lsB_[1],
            FFN / BK, sbase, ra0, rb0, sx0, sx1, acc);

  float bias[4];
  #pragma unroll
  for (int nf = 0; nf < 4; ++nf) bias[nf] = b2[(size_t)e * HIDDEN + n0 + wc * 64 + nf * 16 + cl];
  #pragma unroll
  for (int m = 0; m < 8; ++m) {
    #pragma unroll
    for (int i = 0; i < 4; ++i) {
      int rl = wr * 128 + m * 16 + rg * 4 + i;
      if (m0 + rl < cnt) {
        int p = e * CAP + m0 + rl;
        int tok = pair_tok[p];
        float w = pair_w[p];
        float* op = out + (size_t)tok * HIDDEN + n0 + wc * 64 + cl;
        #pragma unroll
        for (int nf = 0; nf < 4; ++nf)
          atomicAdd(&op[nf * 16], (acc[m][nf][i] + bias[nf]) * w);
      }
    }
  }
}

// ---------------- host ----------------

static constexpr size_t alignup(size_t v) { return (v + 255) & ~size_t(255); }

extern "C" void kernel_launch(void* const* d_in, const int* in_sizes, int n_in,
                              void* d_out, int out_size, void* d_ws, size_t ws_size,
                              hipStream_t stream) {
  const float* x  = (const float*)d_in[0];
  const float* Wg = (const float*)d_in[1];
  const float* bg = (const float*)d_in[2];
  const float* W1 = (const float*)d_in[3];
  const float* b1 = (const float*)d_in[4];
  const float* W2 = (const float*)d_in[5];
  const float* b2 = (const float*)d_in[6];
  float* out = (float*)d_out;

  size_t off = 0;
  char* ws = (char*)d_ws;
  auto take = [&](size_t bytes) { void* p = ws + off; off += alignup(bytes); return p; };
  f16*    xh       = (f16*)take((size_t)NTOK * HIDDEN * 2);
  f16*    w1t      = (f16*)take((size_t)NEXP * FFN * HIDDEN * 2);
  f16*    w2t      = (f16*)take((size_t)NEXP * HIDDEN * FFN * 2);
  f16*    hbuf     = (f16*)take((size_t)NPAIRS * FFN * 2);
  int*    pair_tok = (int*)take((size_t)NEXP * CAP * 4);
  float*  pair_w   = (float*)take((size_t)NEXP * CAP * 4);
  int2*   toke     = (int2*)take((size_t)NTOK * 8);
  float2* tokw     = (float2*)take((size_t)NTOK * 8);
  int*    counts   = (int*)take(64);

  if (off > ws_size) {
    k_sentinel<<<1, 64, 0, stream>>>(out);
    return;
  }

  k_zero<<<2048, 256, 0, stream>>>((float4*)out, NTOK * HIDDEN / 4);
  k_cvt<<<2048, 256, 0, stream>>>(x, xh, NTOK * HIDDEN / 8);
  k_trans<<<dim3(FFN / 32, HIDDEN / 32, NEXP), 256, 0, stream>>>(W1, w1t, HIDDEN, FFN);
  k_trans<<<dim3(HIDDEN / 32, FFN / 32, NEXP), 256, 0, stream>>>(W2, w2t, FFN, HIDDEN);
  k_gate<<<NTOK / 4, 256, 0, stream>>>(x, Wg, bg, toke, tokw);
  k_build<<<NEXP, 256, 0, stream>>>(toke, tokw, pair_tok, pair_w, counts);
  // 16 n-blocks x 64 m-blocks = 1024 blocks (R2 bug: /2 left FFN cols 2048+ unwritten)
  k_ffn1<<<dim3((FFN / BN) * (CAP / BM), 1, NEXP), 512, 0, stream>>>(xh, w1t, b1, hbuf, pair_tok, counts);
  k_ffn2<<<dim3((HIDDEN / BN) * (CAP / BM), 1, NEXP), 512, 0, stream>>>(hbuf, w2t, b2, out, pair_tok, pair_w, counts);
}